// Round 7
// baseline (261.285 us; speedup 1.0000x reference)
//
#include <hip/hip_runtime.h>
#include <hip/hip_bf16.h>

#define S_LEN 2048
#define D_DIM 64
#define NB 16

// exp(x/sqrt(64)) = exp2(x * log2(e)/8)
#define C_EXP 0.1803368801111204f

typedef __attribute__((ext_vector_type(8))) __bf16 bf16x8;
typedef __attribute__((ext_vector_type(4))) __bf16 bf16x4;
typedef __attribute__((ext_vector_type(4))) float f32x4;

// ---------------------------------------------------------------------------
// Kernel A: convert Q and K fp32 -> bf16
// ---------------------------------------------------------------------------
__global__ __launch_bounds__(256) void convert_bf16_kernel(
    const float* __restrict__ qf, const float* __restrict__ kf,
    __bf16* __restrict__ qb, __bf16* __restrict__ kb) {
  const int n4 = NB * S_LEN * D_DIM / 4;
  for (int i = blockIdx.x * blockDim.x + threadIdx.x; i < n4;
       i += gridDim.x * blockDim.x) {
    float4 a = ((const float4*)qf)[i];
    float4 c = ((const float4*)kf)[i];
    bf16x4 oa = {(__bf16)a.x, (__bf16)a.y, (__bf16)a.z, (__bf16)a.w};
    bf16x4 oc = {(__bf16)c.x, (__bf16)c.y, (__bf16)c.z, (__bf16)c.w};
    ((bf16x4*)qb)[i] = oa;
    ((bf16x4*)kb)[i] = oc;
  }
}

// ---------------------------------------------------------------------------
// Kernel B: partial column stats over a q-range (split-q).
// Lpart[qs][b][k] = sum_{q in range} exp(S[q,k]).
// Direct global fragment reads (per-b Q slice = 256KB -> L2-resident);
// no LDS, no barriers: waves free-run.
// ---------------------------------------------------------------------------
__global__ __launch_bounds__(256) void stats_kernel(
    const __bf16* __restrict__ Qb, const __bf16* __restrict__ Kb,
    float* __restrict__ Lpart, int qlen) {
  const int b = blockIdx.y;
  const int kblk = blockIdx.x;
  const int qs = blockIdx.z;
  const int wave = threadIdx.x >> 6;
  const int lane = threadIdx.x & 63;
  const int l16 = lane & 15;
  const int g = lane >> 4;

  const int kbase = kblk * 64 + wave * 16;
  const __bf16* kp = Kb + ((size_t)b * S_LEN + kbase + l16) * D_DIM + g * 8;
  bf16x8 ak0 = *(const bf16x8*)(kp);
  bf16x8 ak1 = *(const bf16x8*)(kp + 32);

  float sacc[4] = {0.f, 0.f, 0.f, 0.f};
  const __bf16* Qbase = Qb + (size_t)b * S_LEN * D_DIM;
  const int qbeg = qs * qlen;

  for (int q0 = qbeg; q0 < qbeg + qlen; q0 += 64) {
#pragma unroll
    for (int qt = 0; qt < 4; ++qt) {
      const __bf16* qp = Qbase + (size_t)(q0 + qt * 16 + l16) * D_DIM + g * 8;
      bf16x8 bq0 = *(const bf16x8*)(qp);
      bf16x8 bq1 = *(const bf16x8*)(qp + 32);
      f32x4 t = __builtin_amdgcn_mfma_f32_16x16x32_bf16(
          ak0, bq0, (f32x4){0.f, 0.f, 0.f, 0.f}, 0, 0, 0);
      t = __builtin_amdgcn_mfma_f32_16x16x32_bf16(ak1, bq1, t, 0, 0, 0);
#pragma unroll
      for (int r4 = 0; r4 < 4; ++r4)
        sacc[r4] += __builtin_amdgcn_exp2f(t[r4] * C_EXP);
    }
  }
#pragma unroll
  for (int r4 = 0; r4 < 4; ++r4) {
    float v = sacc[r4];
    v += __shfl_xor(v, 1);
    v += __shfl_xor(v, 2);
    v += __shfl_xor(v, 4);
    v += __shfl_xor(v, 8);
    if (l16 == 0)
      Lpart[(size_t)qs * NB * S_LEN + (size_t)b * S_LEN + kbase + g * 4 + r4] =
          v;
  }
}

// ---------------------------------------------------------------------------
// Kernel C: Vt[b][d][k] = bf16(V[b][k][d] / L[b][k]),  L = sum of 4 partials
// ---------------------------------------------------------------------------
__global__ __launch_bounds__(256) void scalev_kernel(
    const float* __restrict__ V, const float* __restrict__ Lpart,
    __bf16* __restrict__ Vt) {
  const int b = blockIdx.y;
  const int k = blockIdx.x * 256 + threadIdx.x;
  const size_t NS = (size_t)NB * S_LEN;
  const size_t idx = (size_t)b * S_LEN + k;
  const float L =
      Lpart[idx] + Lpart[NS + idx] + Lpart[2 * NS + idx] + Lpart[3 * NS + idx];
  const float inv = 1.0f / L;
  const float* vrow = V + ((size_t)b * S_LEN + k) * D_DIM;
  __bf16* vt = Vt + (size_t)b * D_DIM * S_LEN + k;
#pragma unroll
  for (int d = 0; d < D_DIM; ++d)
    vt[(size_t)d * S_LEN] = (__bf16)(vrow[d] * inv);
}

// ---------------------------------------------------------------------------
// Kernel D: partial Out = exp(Q·K^T/8) @ Vt over a k-range (split-k).
// Direct global fragment reads (per-b K/Vt slices = 256KB each -> L2);
// no K/V LDS staging, no barriers. Plds is wave-private (C/D -> A-operand
// layout fix for the PV step). Slab output: Op + (ks*NB + b)*S*D.
// ---------------------------------------------------------------------------
__global__ __launch_bounds__(256) void attn_out_kernel(
    const __bf16* __restrict__ Qb, const __bf16* __restrict__ Kb,
    const __bf16* __restrict__ Vt, float* __restrict__ Op, int klen) {
  __shared__ __align__(16) __bf16 Plds[4][16][72];
  const int b = blockIdx.y;
  const int qblk = blockIdx.x;
  const int ks = blockIdx.z;
  const int wave = threadIdx.x >> 6;
  const int lane = threadIdx.x & 63;
  const int l16 = lane & 15;
  const int g = lane >> 4;

  const int qbase = qblk * 64 + wave * 16;
  const __bf16* qp = Qb + ((size_t)b * S_LEN + qbase + l16) * D_DIM + g * 8;
  bf16x8 aq0 = *(const bf16x8*)(qp);
  bf16x8 aq1 = *(const bf16x8*)(qp + 32);

  f32x4 acc[4] = {};
  const __bf16* Kbase = Kb + (size_t)b * S_LEN * D_DIM;
  const __bf16* Vbase = Vt + (size_t)b * D_DIM * S_LEN;
  __bf16(*pl)[72] = Plds[wave];
  const int kbeg = ks * klen;

  for (int k0 = kbeg; k0 < kbeg + klen; k0 += 64) {
    // --- S tile (16 q x 64 k) + exp -> P (wave-private LDS) ---
#pragma unroll
    for (int kt = 0; kt < 4; ++kt) {
      const __bf16* kp = Kbase + (size_t)(k0 + kt * 16 + l16) * D_DIM + g * 8;
      bf16x8 bk0 = *(const bf16x8*)(kp);
      bf16x8 bk1 = *(const bf16x8*)(kp + 32);
      f32x4 t = __builtin_amdgcn_mfma_f32_16x16x32_bf16(
          aq0, bk0, (f32x4){0.f, 0.f, 0.f, 0.f}, 0, 0, 0);
      t = __builtin_amdgcn_mfma_f32_16x16x32_bf16(aq1, bk1, t, 0, 0, 0);
#pragma unroll
      for (int r4 = 0; r4 < 4; ++r4)
        pl[g * 4 + r4][kt * 16 + l16] =
            (__bf16)__builtin_amdgcn_exp2f(t[r4] * C_EXP);
    }
    // --- P back as A-fragments (same wave; lgkmcnt ordering is automatic) ---
    bf16x8 pa0 = *(const bf16x8*)(&pl[l16][g * 8]);
    bf16x8 pa1 = *(const bf16x8*)(&pl[l16][32 + g * 8]);
    // --- PV ---
#pragma unroll
    for (int dt = 0; dt < 4; ++dt) {
      const __bf16* vp = Vbase + (size_t)(dt * 16 + l16) * S_LEN + k0 + g * 8;
      bf16x8 bv0 = *(const bf16x8*)(vp);
      bf16x8 bv1 = *(const bf16x8*)(vp + 32);
      acc[dt] = __builtin_amdgcn_mfma_f32_16x16x32_bf16(pa0, bv0, acc[dt], 0, 0, 0);
      acc[dt] = __builtin_amdgcn_mfma_f32_16x16x32_bf16(pa1, bv1, acc[dt], 0, 0, 0);
    }
  }
  // split-k slab offset (round-5 fix retained)
  float* ob = Op + ((size_t)ks * NB + b) * (size_t)(S_LEN * D_DIM);
#pragma unroll
  for (int dt = 0; dt < 4; ++dt)
#pragma unroll
    for (int r4 = 0; r4 < 4; ++r4)
      ob[(size_t)(qbase + g * 4 + r4) * D_DIM + dt * 16 + l16] = acc[dt][r4];
}

// ---------------------------------------------------------------------------
// Kernel E: reduce split-k partials (float4 vectorized, 1 elem/thread)
// ---------------------------------------------------------------------------
__global__ __launch_bounds__(256) void reduce_kernel(
    const float* __restrict__ Op, float* __restrict__ out, int np) {
  const int i = blockIdx.x * 256 + threadIdx.x;
  const int slab = NB * S_LEN * D_DIM / 4;  // float4 per slab
  const float4* p = (const float4*)Op;
  float4 s = p[i];
  for (int j = 1; j < np; ++j) {
    float4 t = p[i + (size_t)j * slab];
    s.x += t.x; s.y += t.y; s.z += t.z; s.w += t.w;
  }
  ((float4*)out)[i] = s;
}

// ---------------------------------------------------------------------------
extern "C" void kernel_launch(void* const* d_in, const int* in_sizes, int n_in,
                              void* d_out, int out_size, void* d_ws,
                              size_t ws_size, hipStream_t stream) {
  const float* q = (const float*)d_in[0];
  const float* k = (const float*)d_in[1];
  const float* v = (const float*)d_in[2];
  float* out = (float*)d_out;

  char* ws = (char*)d_ws;
  const size_t nelem = (size_t)NB * S_LEN * D_DIM;  // 2,097,152
  __bf16* Qb = (__bf16*)ws;                          // 4 MB @ 0
  __bf16* Kb = (__bf16*)(ws + nelem * 2);            // 4 MB @ 4M
  __bf16* Vt = (__bf16*)(ws + nelem * 4);            // 4 MB @ 8M
  float* Lp = (float*)(ws + nelem * 6);              // 512 KB @ 12M
  float* Op = (float*)(ws + (13u << 20));            // up to 32 MB @ 13M

  // split-k factor limited by workspace for fp32 partials
  int ksplit = 1;
  if (ws_size >= (13u << 20) + 4 * nelem * 4) ksplit = 4;
  else if (ws_size >= (13u << 20) + 2 * nelem * 4) ksplit = 2;

  convert_bf16_kernel<<<1024, 256, 0, stream>>>(q, k, Qb, Kb);
  stats_kernel<<<dim3(32, 16, 4), 256, 0, stream>>>(Qb, Kb, Lp, S_LEN / 4);
  scalev_kernel<<<dim3(8, 16), 256, 0, stream>>>(v, Lp, Vt);
  float* attn_dst = (ksplit == 1) ? out : Op;
  attn_out_kernel<<<dim3(32, 16, ksplit), 256, 0, stream>>>(Qb, Kb, Vt,
                                                            attn_dst,
                                                            S_LEN / ksplit);
  if (ksplit > 1)
    reduce_kernel<<<(int)(nelem / 4 / 256), 256, 0, stream>>>(Op, out, ksplit);
}

// Round 11
// 135.286 us; speedup vs baseline: 1.9314x; 1.9314x over previous
//
#include <hip/hip_runtime.h>
#include <hip/hip_bf16.h>

#define S_LEN 2048
#define D_DIM 64
#define NB 16

// exp(x/sqrt(64)) = exp2(x * log2(e)/8)
#define C_EXP 0.1803368801111204f

typedef __attribute__((ext_vector_type(8))) __bf16 bf16x8;
typedef __attribute__((ext_vector_type(4))) __bf16 bf16x4;
typedef __attribute__((ext_vector_type(4))) float f32x4;

// global -> LDS direct DMA, 16B per lane (wave-uniform base + lane*16).
#define GLOAD16(gp, lp)                                              \
  __builtin_amdgcn_global_load_lds(                                  \
      (const __attribute__((address_space(1))) void*)(gp),           \
      (__attribute__((address_space(3))) void*)(lp), 16, 0, 0)

// ---------------------------------------------------------------------------
// Kernel A: convert Q and K fp32 -> bf16
// ---------------------------------------------------------------------------
__global__ __launch_bounds__(256) void convert_bf16_kernel(
    const float* __restrict__ qf, const float* __restrict__ kf,
    __bf16* __restrict__ qb, __bf16* __restrict__ kb) {
  const int n4 = NB * S_LEN * D_DIM / 4;
  for (int i = blockIdx.x * blockDim.x + threadIdx.x; i < n4;
       i += gridDim.x * blockDim.x) {
    float4 a = ((const float4*)qf)[i];
    float4 c = ((const float4*)kf)[i];
    bf16x4 oa = {(__bf16)a.x, (__bf16)a.y, (__bf16)a.z, (__bf16)a.w};
    bf16x4 oc = {(__bf16)c.x, (__bf16)c.y, (__bf16)c.z, (__bf16)c.w};
    ((bf16x4*)qb)[i] = oa;
    ((bf16x4*)kb)[i] = oc;
  }
}

// ---------------------------------------------------------------------------
// Kernel B: partial column stats over a q-range (split-q).
// wg owns 128 k-rows (wave owns 32 = 2 row-groups); Q tiles staged in LDS
// (swizzled gload_lds) and shared by all 4 waves -> 16 MFMA/wave per 8KB tile.
// ---------------------------------------------------------------------------
__global__ __launch_bounds__(256) void stats_kernel(
    const __bf16* __restrict__ Qb, const __bf16* __restrict__ Kb,
    float* __restrict__ Lpart, int qlen) {
  __shared__ __align__(16) __bf16 QT[4096];  // 64 q-rows x 64 d, swizzled
  const int b = blockIdx.y;
  const int kblk = blockIdx.x;              // 0..15 (128 k-rows each)
  const int qs = blockIdx.z;
  const int tid = threadIdx.x;
  const int wave = tid >> 6;
  const int lane = tid & 63;
  const int l16 = lane & 15;
  const int g = lane >> 4;

  const int kbase = kblk * 128 + wave * 32;
  bf16x8 ak[2][2];
#pragma unroll
  for (int rg = 0; rg < 2; ++rg) {
    const __bf16* kp =
        Kb + ((size_t)b * S_LEN + kbase + rg * 16 + l16) * D_DIM + g * 8;
    ak[rg][0] = *(const bf16x8*)(kp);
    ak[rg][1] = *(const bf16x8*)(kp + 32);
  }

  const int srow = tid >> 3;                       // 0..31
  const int scol = 8 * ((tid & 7) ^ (srow & 7));   // pre-swizzled global col

  float sacc[2][4] = {};
  const __bf16* Qbase = Qb + (size_t)b * S_LEN * D_DIM;
  const int qbeg = qs * qlen;

  for (int q0 = qbeg; q0 < qbeg + qlen; q0 += 64) {
    __syncthreads();
#pragma unroll
    for (int h = 0; h < 2; ++h)
      GLOAD16(Qbase + (size_t)(q0 + h * 32 + srow) * D_DIM + scol,
              (char*)QT + h * 4096 + (size_t)tid * 16);
    asm volatile("s_waitcnt vmcnt(0)" ::: "memory");
    __syncthreads();

#pragma unroll
    for (int qt = 0; qt < 4; ++qt) {
      const int r = qt * 16 + l16;
      bf16x8 bq0 = *(const bf16x8*)(QT + r * 64 + 8 * (g ^ (r & 7)));
      bf16x8 bq1 = *(const bf16x8*)(QT + r * 64 + 8 * ((g + 4) ^ (r & 7)));
#pragma unroll
      for (int rg = 0; rg < 2; ++rg) {
        f32x4 t = __builtin_amdgcn_mfma_f32_16x16x32_bf16(
            ak[rg][0], bq0, (f32x4){0.f, 0.f, 0.f, 0.f}, 0, 0, 0);
        t = __builtin_amdgcn_mfma_f32_16x16x32_bf16(ak[rg][1], bq1, t, 0, 0, 0);
#pragma unroll
        for (int r4 = 0; r4 < 4; ++r4)
          sacc[rg][r4] += __builtin_amdgcn_exp2f(t[r4] * C_EXP);
      }
    }
  }
  // reduce across the 16 q-columns (lanes sharing g), write L partials
#pragma unroll
  for (int rg = 0; rg < 2; ++rg)
#pragma unroll
    for (int r4 = 0; r4 < 4; ++r4) {
      float v = sacc[rg][r4];
      v += __shfl_xor(v, 1);
      v += __shfl_xor(v, 2);
      v += __shfl_xor(v, 4);
      v += __shfl_xor(v, 8);
      if (l16 == 0)
        Lpart[(size_t)qs * NB * S_LEN + (size_t)b * S_LEN + kbase + rg * 16 +
              g * 4 + r4] = v;
    }
}

// ---------------------------------------------------------------------------
// Kernel C: Vt[b][d][k] = bf16(V[b][k][d] / L[b][k]),  L = sum of 4 partials
// ---------------------------------------------------------------------------
__global__ __launch_bounds__(256) void scalev_kernel(
    const float* __restrict__ V, const float* __restrict__ Lpart,
    __bf16* __restrict__ Vt) {
  const int b = blockIdx.y;
  const int k = blockIdx.x * 256 + threadIdx.x;
  const size_t NS = (size_t)NB * S_LEN;
  const size_t idx = (size_t)b * S_LEN + k;
  const float L =
      Lpart[idx] + Lpart[NS + idx] + Lpart[2 * NS + idx] + Lpart[3 * NS + idx];
  const float inv = 1.0f / L;
  const float* vrow = V + ((size_t)b * S_LEN + k) * D_DIM;
  __bf16* vt = Vt + (size_t)b * D_DIM * S_LEN + k;
#pragma unroll
  for (int d = 0; d < D_DIM; ++d)
    vt[(size_t)d * S_LEN] = (__bf16)(vrow[d] * inv);
}

// ---------------------------------------------------------------------------
// Kernel D: partial Out = exp(Q·K^T/8) @ Vt over a k-range (split-k).
// wg owns 128 q-rows (wave owns 32 = 2 row-groups); K/Vt tiles staged in LDS
// via swizzled gload_lds -> 32 MFMA/wave per 16KB staged tile (2x round 6).
// Plds is wave-private (C/D -> A-operand layout fix). Slab: Op+(ks*NB+b)*S*D.
// ---------------------------------------------------------------------------
__global__ __launch_bounds__(256) void attn_out_kernel(
    const __bf16* __restrict__ Qb, const __bf16* __restrict__ Kb,
    const __bf16* __restrict__ Vt, float* __restrict__ Op, int klen) {
  __shared__ __align__(16) __bf16 KT[4096];       // 64 k-rows x 64 d, swizzled
  __shared__ __align__(16) __bf16 VT[4096];       // 64 d-rows x 64 k, swizzled
  __shared__ __align__(16) __bf16 Plds[4][32][72];
  const int b = blockIdx.y;
  const int qblk = blockIdx.x;                    // 0..15 (128 q-rows each)
  const int ks = blockIdx.z;
  const int tid = threadIdx.x;
  const int wave = tid >> 6;
  const int lane = tid & 63;
  const int l16 = lane & 15;
  const int g = lane >> 4;

  const int qbase = qblk * 128 + wave * 32;
  bf16x8 aq[2][2];
#pragma unroll
  for (int rg = 0; rg < 2; ++rg) {
    const __bf16* qp =
        Qb + ((size_t)b * S_LEN + qbase + rg * 16 + l16) * D_DIM + g * 8;
    aq[rg][0] = *(const bf16x8*)(qp);
    aq[rg][1] = *(const bf16x8*)(qp + 32);
  }

  f32x4 acc[2][4] = {};
  const int srow = tid >> 3;
  const int scol = 8 * ((tid & 7) ^ (srow & 7));
  const __bf16* Kbase = Kb + (size_t)b * S_LEN * D_DIM;
  const __bf16* Vbase = Vt + (size_t)b * D_DIM * S_LEN;
  __bf16(*pl)[72] = Plds[wave];
  const int kbeg = ks * klen;

  for (int k0 = kbeg; k0 < kbeg + klen; k0 += 64) {
    __syncthreads();
#pragma unroll
    for (int h = 0; h < 2; ++h) {
      GLOAD16(Kbase + (size_t)(k0 + h * 32 + srow) * D_DIM + scol,
              (char*)KT + h * 4096 + (size_t)tid * 16);
      GLOAD16(Vbase + (size_t)(h * 32 + srow) * S_LEN + k0 + scol,
              (char*)VT + h * 4096 + (size_t)tid * 16);
    }
    asm volatile("s_waitcnt vmcnt(0)" ::: "memory");
    __syncthreads();

    // --- S tile (32 q x 64 k) + exp -> P (wave-private LDS) ---
#pragma unroll
    for (int kt = 0; kt < 4; ++kt) {
      const int r = kt * 16 + l16;
      bf16x8 bk0 = *(const bf16x8*)(KT + r * 64 + 8 * (g ^ (r & 7)));
      bf16x8 bk1 = *(const bf16x8*)(KT + r * 64 + 8 * ((g + 4) ^ (r & 7)));
#pragma unroll
      for (int rg = 0; rg < 2; ++rg) {
        f32x4 t = __builtin_amdgcn_mfma_f32_16x16x32_bf16(
            aq[rg][0], bk0, (f32x4){0.f, 0.f, 0.f, 0.f}, 0, 0, 0);
        t = __builtin_amdgcn_mfma_f32_16x16x32_bf16(aq[rg][1], bk1, t, 0, 0, 0);
#pragma unroll
        for (int r4 = 0; r4 < 4; ++r4)
          pl[rg * 16 + g * 4 + r4][kt * 16 + l16] =
              (__bf16)__builtin_amdgcn_exp2f(t[r4] * C_EXP);
      }
    }
    // --- P back as A-fragments (same wave; no barrier needed) ---
    bf16x8 pa[2][2];
#pragma unroll
    for (int rg = 0; rg < 2; ++rg) {
      pa[rg][0] = *(const bf16x8*)(&pl[rg * 16 + l16][g * 8]);
      pa[rg][1] = *(const bf16x8*)(&pl[rg * 16 + l16][32 + g * 8]);
    }
    // --- PV ---
#pragma unroll
    for (int dt = 0; dt < 4; ++dt) {
      const int rd = dt * 16 + l16;
      bf16x8 bv0 = *(const bf16x8*)(VT + rd * 64 + 8 * (g ^ (rd & 7)));
      bf16x8 bv1 = *(const bf16x8*)(VT + rd * 64 + 8 * ((g + 4) ^ (rd & 7)));
#pragma unroll
      for (int rg = 0; rg < 2; ++rg) {
        acc[rg][dt] =
            __builtin_amdgcn_mfma_f32_16x16x32_bf16(pa[rg][0], bv0, acc[rg][dt], 0, 0, 0);
        acc[rg][dt] =
            __builtin_amdgcn_mfma_f32_16x16x32_bf16(pa[rg][1], bv1, acc[rg][dt], 0, 0, 0);
      }
    }
  }
  // split-k slab offset
  float* ob = Op + ((size_t)ks * NB + b) * (size_t)(S_LEN * D_DIM);
#pragma unroll
  for (int rg = 0; rg < 2; ++rg)
#pragma unroll
    for (int dt = 0; dt < 4; ++dt)
#pragma unroll
      for (int r4 = 0; r4 < 4; ++r4)
        ob[(size_t)(qbase + rg * 16 + g * 4 + r4) * D_DIM + dt * 16 + l16] =
            acc[rg][dt][r4];
}

// ---------------------------------------------------------------------------
// Kernel E: reduce split-k partials (float4 vectorized, 1 elem/thread)
// ---------------------------------------------------------------------------
__global__ __launch_bounds__(256) void reduce_kernel(
    const float* __restrict__ Op, float* __restrict__ out, int np) {
  const int i = blockIdx.x * 256 + threadIdx.x;
  const int slab = NB * S_LEN * D_DIM / 4;  // float4 per slab
  const float4* p = (const float4*)Op;
  float4 s = p[i];
  for (int j = 1; j < np; ++j) {
    float4 t = p[i + (size_t)j * slab];
    s.x += t.x; s.y += t.y; s.z += t.z; s.w += t.w;
  }
  ((float4*)out)[i] = s;
}

// ---------------------------------------------------------------------------
extern "C" void kernel_launch(void* const* d_in, const int* in_sizes, int n_in,
                              void* d_out, int out_size, void* d_ws,
                              size_t ws_size, hipStream_t stream) {
  const float* q = (const float*)d_in[0];
  const float* k = (const float*)d_in[1];
  const float* v = (const float*)d_in[2];
  float* out = (float*)d_out;

  char* ws = (char*)d_ws;
  const size_t nelem = (size_t)NB * S_LEN * D_DIM;  // 2,097,152
  __bf16* Qb = (__bf16*)ws;                          // 4 MB @ 0
  __bf16* Kb = (__bf16*)(ws + nelem * 2);            // 4 MB @ 4M
  __bf16* Vt = (__bf16*)(ws + nelem * 4);            // 4 MB @ 8M
  float* Lp = (float*)(ws + nelem * 6);              // 512 KB @ 12M
  float* Op = (float*)(ws + (13u << 20));            // up to 32 MB @ 13M

  // split-k factor limited by workspace for fp32 partials
  int ksplit = 1;
  if (ws_size >= (13u << 20) + 4 * nelem * 4) ksplit = 4;
  else if (ws_size >= (13u << 20) + 2 * nelem * 4) ksplit = 2;

  convert_bf16_kernel<<<1024, 256, 0, stream>>>(q, k, Qb, Kb);
  stats_kernel<<<dim3(16, 16, 4), 256, 0, stream>>>(Qb, Kb, Lp, S_LEN / 4);
  scalev_kernel<<<dim3(8, 16), 256, 0, stream>>>(v, Lp, Vt);
  float* attn_dst = (ksplit == 1) ? out : Op;
  attn_out_kernel<<<dim3(16, 16, ksplit), 256, 0, stream>>>(Qb, Kb, Vt,
                                                            attn_dst,
                                                            S_LEN / ksplit);
  if (ksplit > 1)
    reduce_kernel<<<(int)(nelem / 4 / 256), 256, 0, stream>>>(Op, out, ksplit);
}

// Round 12
// 131.060 us; speedup vs baseline: 1.9936x; 1.0322x over previous
//
#include <hip/hip_runtime.h>
#include <hip/hip_bf16.h>

#define S_LEN 2048
#define D_DIM 64
#define NB 16

// exp(x/sqrt(64)) = exp2(x * log2(e)/8)
#define C_EXP 0.1803368801111204f

typedef __attribute__((ext_vector_type(8))) __bf16 bf16x8;
typedef __attribute__((ext_vector_type(4))) __bf16 bf16x4;
typedef __attribute__((ext_vector_type(4))) float f32x4;

// global -> LDS direct DMA, 16B per lane (wave-uniform base + lane*16).
#define GLOAD16(gp, lp)                                              \
  __builtin_amdgcn_global_load_lds(                                  \
      (const __attribute__((address_space(1))) void*)(gp),           \
      (__attribute__((address_space(3))) void*)(lp), 16, 0, 0)

// raw barrier with compile-time memory fence (no vmcnt/lgkm drain)
#define BAR() asm volatile("s_barrier" ::: "memory")
#define WAIT_VM(n) asm volatile("s_waitcnt vmcnt(" #n ")" ::: "memory")

// ---------------------------------------------------------------------------
// Kernel A: convert Q and K fp32 -> bf16
// ---------------------------------------------------------------------------
__global__ __launch_bounds__(256) void convert_bf16_kernel(
    const float* __restrict__ qf, const float* __restrict__ kf,
    __bf16* __restrict__ qb, __bf16* __restrict__ kb) {
  const int n4 = NB * S_LEN * D_DIM / 4;
  for (int i = blockIdx.x * blockDim.x + threadIdx.x; i < n4;
       i += gridDim.x * blockDim.x) {
    float4 a = ((const float4*)qf)[i];
    float4 c = ((const float4*)kf)[i];
    bf16x4 oa = {(__bf16)a.x, (__bf16)a.y, (__bf16)a.z, (__bf16)a.w};
    bf16x4 oc = {(__bf16)c.x, (__bf16)c.y, (__bf16)c.z, (__bf16)c.w};
    ((bf16x4*)qb)[i] = oa;
    ((bf16x4*)kb)[i] = oc;
  }
}

// ---------------------------------------------------------------------------
// Kernel B: partial column stats over a q-range (split-q), 2-phase dbuf.
// wg owns 128 k-rows (wave 32); Q tiles double-buffered in LDS; issue-next
// before counted vmcnt(2) wait -> stage latency hides under 16 MFMA + 32 exp.
// ---------------------------------------------------------------------------
__global__ __launch_bounds__(256) void stats_kernel(
    const __bf16* __restrict__ Qb, const __bf16* __restrict__ Kb,
    float* __restrict__ Lpart, int qlen) {
  __shared__ __align__(16) __bf16 QT[2][4096];  // 2 x (64 q-rows x 64 d)
  const int b = blockIdx.y;
  const int kblk = blockIdx.x;              // 0..15 (128 k-rows each)
  const int qs = blockIdx.z;
  const int tid = threadIdx.x;
  const int wave = tid >> 6;
  const int lane = tid & 63;
  const int l16 = lane & 15;
  const int g = lane >> 4;

  const int kbase = kblk * 128 + wave * 32;
  bf16x8 ak[2][2];
#pragma unroll
  for (int rg = 0; rg < 2; ++rg) {
    const __bf16* kp =
        Kb + ((size_t)b * S_LEN + kbase + rg * 16 + l16) * D_DIM + g * 8;
    ak[rg][0] = *(const bf16x8*)(kp);
    ak[rg][1] = *(const bf16x8*)(kp + 32);
  }

  const int srow = tid >> 3;                       // 0..31
  const int scol = 8 * ((tid & 7) ^ (srow & 7));   // pre-swizzled global col

  float sacc[2][4] = {};
  const __bf16* Qbase = Qb + (size_t)b * S_LEN * D_DIM;
  const int qbeg = qs * qlen;
  const int qend = qbeg + qlen;

  // prologue: stage Q(0) into buf 0
#pragma unroll
  for (int h = 0; h < 2; ++h)
    GLOAD16(Qbase + (size_t)(qbeg + h * 32 + srow) * D_DIM + scol,
            (char*)QT[0] + h * 4096 + (size_t)tid * 16);

  int cur = 0;
  for (int q0 = qbeg; q0 < qend; q0 += 64, cur ^= 1) {
    const bool haveNext = (q0 + 64 < qend);
    if (haveNext) {  // issue next tile into other buffer BEFORE waiting
#pragma unroll
      for (int h = 0; h < 2; ++h)
        GLOAD16(Qbase + (size_t)(q0 + 64 + h * 32 + srow) * D_DIM + scol,
                (char*)QT[cur ^ 1] + h * 4096 + (size_t)tid * 16);
      WAIT_VM(2);  // wait only for Q(t); Q(t+1) stays in flight
    } else {
      WAIT_VM(0);
    }
    BAR();
    const __bf16* qt = QT[cur];
#pragma unroll
    for (int qtl = 0; qtl < 4; ++qtl) {
      const int r = qtl * 16 + l16;
      bf16x8 bq0 = *(const bf16x8*)(qt + r * 64 + 8 * (g ^ (r & 7)));
      bf16x8 bq1 = *(const bf16x8*)(qt + r * 64 + 8 * ((g + 4) ^ (r & 7)));
#pragma unroll
      for (int rg = 0; rg < 2; ++rg) {
        f32x4 t = __builtin_amdgcn_mfma_f32_16x16x32_bf16(
            ak[rg][0], bq0, (f32x4){0.f, 0.f, 0.f, 0.f}, 0, 0, 0);
        t = __builtin_amdgcn_mfma_f32_16x16x32_bf16(ak[rg][1], bq1, t, 0, 0, 0);
#pragma unroll
        for (int r4 = 0; r4 < 4; ++r4)
          sacc[rg][r4] += __builtin_amdgcn_exp2f(t[r4] * C_EXP);
      }
    }
    BAR();  // all waves done with QT[cur] before it is re-staged
  }
  // reduce across the 16 q-columns (lanes sharing g), write L partials
#pragma unroll
  for (int rg = 0; rg < 2; ++rg)
#pragma unroll
    for (int r4 = 0; r4 < 4; ++r4) {
      float v = sacc[rg][r4];
      v += __shfl_xor(v, 1);
      v += __shfl_xor(v, 2);
      v += __shfl_xor(v, 4);
      v += __shfl_xor(v, 8);
      if (l16 == 0)
        Lpart[(size_t)qs * NB * S_LEN + (size_t)b * S_LEN + kbase + rg * 16 +
              g * 4 + r4] = v;
    }
}

// ---------------------------------------------------------------------------
// Kernel C: Vt[b][d][k] = bf16(V[b][k][d] / L[b][k]),  L = sum of 4 partials
// ---------------------------------------------------------------------------
__global__ __launch_bounds__(256) void scalev_kernel(
    const float* __restrict__ V, const float* __restrict__ Lpart,
    __bf16* __restrict__ Vt) {
  const int b = blockIdx.y;
  const int k = blockIdx.x * 256 + threadIdx.x;
  const size_t NS = (size_t)NB * S_LEN;
  const size_t idx = (size_t)b * S_LEN + k;
  const float L =
      Lpart[idx] + Lpart[NS + idx] + Lpart[2 * NS + idx] + Lpart[3 * NS + idx];
  const float inv = 1.0f / L;
  const float* vrow = V + ((size_t)b * S_LEN + k) * D_DIM;
  __bf16* vt = Vt + (size_t)b * D_DIM * S_LEN + k;
#pragma unroll
  for (int d = 0; d < D_DIM; ++d)
    vt[(size_t)d * S_LEN] = (__bf16)(vrow[d] * inv);
}

// ---------------------------------------------------------------------------
// Kernel D: partial Out = exp(Q·K^T/8) @ Vt over a k-range (split-k),
// interleaved K/V pipeline (T3/T4-minimal): K(t+1) stage flies during PV(t),
// V(t+1) stage flies during S(t+1). Counted vmcnt(2) mid-loop, never 0.
// Single K/V buffers (LDS unchanged -> 4 wg/CU, grid = exact residency).
// ---------------------------------------------------------------------------
__global__ __launch_bounds__(256) void attn_out_kernel(
    const __bf16* __restrict__ Qb, const __bf16* __restrict__ Kb,
    const __bf16* __restrict__ Vt, float* __restrict__ Op, int klen) {
  __shared__ __align__(16) __bf16 KT[4096];       // 64 k-rows x 64 d, swizzled
  __shared__ __align__(16) __bf16 VT[4096];       // 64 d-rows x 64 k, swizzled
  __shared__ __align__(16) __bf16 Plds[4][32][72];
  const int b = blockIdx.y;
  const int qblk = blockIdx.x;                    // 0..15 (128 q-rows each)
  const int ks = blockIdx.z;
  const int tid = threadIdx.x;
  const int wave = tid >> 6;
  const int lane = tid & 63;
  const int l16 = lane & 15;
  const int g = lane >> 4;

  const int qbase = qblk * 128 + wave * 32;
  bf16x8 aq[2][2];
#pragma unroll
  for (int rg = 0; rg < 2; ++rg) {
    const __bf16* qp =
        Qb + ((size_t)b * S_LEN + qbase + rg * 16 + l16) * D_DIM + g * 8;
    aq[rg][0] = *(const bf16x8*)(qp);
    aq[rg][1] = *(const bf16x8*)(qp + 32);
  }

  f32x4 acc[2][4] = {};
  const int srow = tid >> 3;
  const int scol = 8 * ((tid & 7) ^ (srow & 7));
  const __bf16* Kbase = Kb + (size_t)b * S_LEN * D_DIM;
  const __bf16* Vbase = Vt + (size_t)b * D_DIM * S_LEN;
  __bf16(*pl)[72] = Plds[wave];
  const int kbeg = ks * klen;
  const int kend = kbeg + klen;

  // prologue: issue K(0) then V(0)  (4 loads outstanding per thread)
#pragma unroll
  for (int h = 0; h < 2; ++h)
    GLOAD16(Kbase + (size_t)(kbeg + h * 32 + srow) * D_DIM + scol,
            (char*)KT + h * 4096 + (size_t)tid * 16);
#pragma unroll
  for (int h = 0; h < 2; ++h)
    GLOAD16(Vbase + (size_t)(h * 32 + srow) * S_LEN + kbeg + scol,
            (char*)VT + h * 4096 + (size_t)tid * 16);

  for (int k0 = kbeg; k0 < kend; k0 += 64) {
    const bool haveNext = (k0 + 64 < kend);
    // --- K(t) ready: oldest 2 of {K(t),V(t)} ---
    WAIT_VM(2);
    BAR();
    // --- S tile (32 q x 64 k) + exp -> P (wave-private LDS) ---
#pragma unroll
    for (int kt = 0; kt < 4; ++kt) {
      const int r = kt * 16 + l16;
      bf16x8 bk0 = *(const bf16x8*)(KT + r * 64 + 8 * (g ^ (r & 7)));
      bf16x8 bk1 = *(const bf16x8*)(KT + r * 64 + 8 * ((g + 4) ^ (r & 7)));
#pragma unroll
      for (int rg = 0; rg < 2; ++rg) {
        f32x4 t = __builtin_amdgcn_mfma_f32_16x16x32_bf16(
            aq[rg][0], bk0, (f32x4){0.f, 0.f, 0.f, 0.f}, 0, 0, 0);
        t = __builtin_amdgcn_mfma_f32_16x16x32_bf16(aq[rg][1], bk1, t, 0, 0, 0);
#pragma unroll
        for (int r4 = 0; r4 < 4; ++r4)
          pl[rg * 16 + g * 4 + r4][kt * 16 + l16] =
              (__bf16)__builtin_amdgcn_exp2f(t[r4] * C_EXP);
      }
    }
    BAR();  // all waves done reading KT
    // --- issue K(t+1) into KT; its DMA flies during PV(t) ---
    if (haveNext) {
#pragma unroll
      for (int h = 0; h < 2; ++h)
        GLOAD16(Kbase + (size_t)(k0 + 64 + h * 32 + srow) * D_DIM + scol,
                (char*)KT + h * 4096 + (size_t)tid * 16);
      WAIT_VM(2);  // V(t) ready (oldest 2); K(t+1) stays in flight
    } else {
      WAIT_VM(0);  // last tile: drain V(t)
    }
    BAR();
    // --- P back as A-fragments (same wave; no barrier needed) ---
    bf16x8 pa[2][2];
#pragma unroll
    for (int rg = 0; rg < 2; ++rg) {
      pa[rg][0] = *(const bf16x8*)(&pl[rg * 16 + l16][g * 8]);
      pa[rg][1] = *(const bf16x8*)(&pl[rg * 16 + l16][32 + g * 8]);
    }
    // --- PV ---
#pragma unroll
    for (int dt = 0; dt < 4; ++dt) {
      const int rd = dt * 16 + l16;
      bf16x8 bv0 = *(const bf16x8*)(VT + rd * 64 + 8 * (g ^ (rd & 7)));
      bf16x8 bv1 = *(const bf16x8*)(VT + rd * 64 + 8 * ((g + 4) ^ (rd & 7)));
#pragma unroll
      for (int rg = 0; rg < 2; ++rg) {
        acc[rg][dt] = __builtin_amdgcn_mfma_f32_16x16x32_bf16(
            pa[rg][0], bv0, acc[rg][dt], 0, 0, 0);
        acc[rg][dt] = __builtin_amdgcn_mfma_f32_16x16x32_bf16(
            pa[rg][1], bv1, acc[rg][dt], 0, 0, 0);
      }
    }
    BAR();  // all waves done reading VT
    // --- issue V(t+1) into VT; its DMA flies during S(t+1) ---
    if (haveNext) {
#pragma unroll
      for (int h = 0; h < 2; ++h)
        GLOAD16(Vbase + (size_t)(h * 32 + srow) * S_LEN + (k0 + 64) + scol,
                (char*)VT + h * 4096 + (size_t)tid * 16);
    }
  }
  // split-k slab offset
  float* ob = Op + ((size_t)ks * NB + b) * (size_t)(S_LEN * D_DIM);
#pragma unroll
  for (int rg = 0; rg < 2; ++rg)
#pragma unroll
    for (int dt = 0; dt < 4; ++dt)
#pragma unroll
      for (int r4 = 0; r4 < 4; ++r4)
        ob[(size_t)(qbase + rg * 16 + g * 4 + r4) * D_DIM + dt * 16 + l16] =
            acc[rg][dt][r4];
}

// ---------------------------------------------------------------------------
// Kernel E: reduce split-k partials (float4 vectorized, 1 elem/thread)
// ---------------------------------------------------------------------------
__global__ __launch_bounds__(256) void reduce_kernel(
    const float* __restrict__ Op, float* __restrict__ out, int np) {
  const int i = blockIdx.x * 256 + threadIdx.x;
  const int slab = NB * S_LEN * D_DIM / 4;  // float4 per slab
  const float4* p = (const float4*)Op;
  float4 s = p[i];
  for (int j = 1; j < np; ++j) {
    float4 t = p[i + (size_t)j * slab];
    s.x += t.x; s.y += t.y; s.z += t.z; s.w += t.w;
  }
  ((float4*)out)[i] = s;
}

// ---------------------------------------------------------------------------
extern "C" void kernel_launch(void* const* d_in, const int* in_sizes, int n_in,
                              void* d_out, int out_size, void* d_ws,
                              size_t ws_size, hipStream_t stream) {
  const float* q = (const float*)d_in[0];
  const float* k = (const float*)d_in[1];
  const float* v = (const float*)d_in[2];
  float* out = (float*)d_out;

  char* ws = (char*)d_ws;
  const size_t nelem = (size_t)NB * S_LEN * D_DIM;  // 2,097,152
  __bf16* Qb = (__bf16*)ws;                          // 4 MB @ 0
  __bf16* Kb = (__bf16*)(ws + nelem * 2);            // 4 MB @ 4M
  __bf16* Vt = (__bf16*)(ws + nelem * 4);            // 4 MB @ 8M
  float* Lp = (float*)(ws + nelem * 6);              // 512 KB @ 12M
  float* Op = (float*)(ws + (13u << 20));            // up to 32 MB @ 13M

  // split-k factor limited by workspace for fp32 partials
  int ksplit = 1;
  if (ws_size >= (13u << 20) + 4 * nelem * 4) ksplit = 4;
  else if (ws_size >= (13u << 20) + 2 * nelem * 4) ksplit = 2;

  convert_bf16_kernel<<<1024, 256, 0, stream>>>(q, k, Qb, Kb);
  stats_kernel<<<dim3(16, 16, 4), 256, 0, stream>>>(Qb, Kb, Lp, S_LEN / 4);
  scalev_kernel<<<dim3(8, 16), 256, 0, stream>>>(v, Lp, Vt);
  float* attn_dst = (ksplit == 1) ? out : Op;
  attn_out_kernel<<<dim3(16, 16, ksplit), 256, 0, stream>>>(Qb, Kb, Vt,
                                                            attn_dst,
                                                            S_LEN / ksplit);
  if (ksplit > 1)
    reduce_kernel<<<(int)(nelem / 4 / 256), 256, 0, stream>>>(Op, out, ksplit);
}

// Round 14
// 126.776 us; speedup vs baseline: 2.0610x; 1.0338x over previous
//
#include <hip/hip_runtime.h>
#include <hip/hip_bf16.h>

#define S_LEN 2048
#define D_DIM 64
#define NB 16

// exp(x/sqrt(64)) = exp2(x * log2(e)/8)
#define C_EXP 0.1803368801111204f

typedef __attribute__((ext_vector_type(8))) __bf16 bf16x8;
typedef __attribute__((ext_vector_type(4))) __bf16 bf16x4;
typedef __attribute__((ext_vector_type(4))) float f32x4;
typedef __attribute__((ext_vector_type(16))) float f32x16;
typedef __attribute__((ext_vector_type(4))) unsigned u32x4;

// global -> LDS direct DMA, 16B per lane (wave-uniform base + lane*16).
#define GLOAD16(gp, lp)                                              \
  __builtin_amdgcn_global_load_lds(                                  \
      (const __attribute__((address_space(1))) void*)(gp),           \
      (__attribute__((address_space(3))) void*)(lp), 16, 0, 0)

#define BAR() asm volatile("s_barrier" ::: "memory")
#define WAIT_VM(n) asm volatile("s_waitcnt vmcnt(" #n ")" ::: "memory")

// pack two f32 -> one u32 of 2 bf16 (lo = a, hi = b), RNE
__device__ __forceinline__ unsigned cvt_pk_bf16(float a, float b) {
  unsigned r;
  asm("v_cvt_pk_bf16_f32 %0, %1, %2" : "=v"(r) : "v"(a), "v"(b));
  return r;
}
// in place: a' = (lane<32 ? a : b[lane-32]);  b' = (lane<32 ? a[lane+32] : b)
#define PLSWAP(a, b) \
  asm volatile("v_permlane32_swap_b32 %0, %1" : "+v"(a), "+v"(b))

// LDS bank-spread swizzle: stored 16B-slot for logical slot j of row r.
// rows r, r+8, r+16, r+24 reading the same logical j land in distinct slots.
__device__ __forceinline__ int swz(int j, int r) {
  return ((j ^ (r & 7)) + (r >> 3)) & 7;
}
// inverse: logical slot staged by stored-slot t of row r
__device__ __forceinline__ int iswz(int t, int r) {
  return ((t - (r >> 3)) & 7) ^ (r & 7);
}

// ---------------------------------------------------------------------------
// Kernel A: convert Q and K fp32 -> bf16
// ---------------------------------------------------------------------------
__global__ __launch_bounds__(256) void convert_bf16_kernel(
    const float* __restrict__ qf, const float* __restrict__ kf,
    __bf16* __restrict__ qb, __bf16* __restrict__ kb) {
  const int n4 = NB * S_LEN * D_DIM / 4;
  for (int i = blockIdx.x * blockDim.x + threadIdx.x; i < n4;
       i += gridDim.x * blockDim.x) {
    float4 a = ((const float4*)qf)[i];
    float4 c = ((const float4*)kf)[i];
    bf16x4 oa = {(__bf16)a.x, (__bf16)a.y, (__bf16)a.z, (__bf16)a.w};
    bf16x4 oc = {(__bf16)c.x, (__bf16)c.y, (__bf16)c.z, (__bf16)c.w};
    ((bf16x4*)qb)[i] = oa;
    ((bf16x4*)kb)[i] = oc;
  }
}

// ---------------------------------------------------------------------------
// Kernel B: partial column stats over a q-range (split-q), 32x32 swapped MFMA.
// S^T = K·Q^T: lane holds col q=lane&31, rows k'=(r&3)+8(r>>2)+4*hi.
// L[k'] = sum_q exp(S^T[k',q]) -> accumulate per-reg, xor-reduce over lane&31.
// Q tiles double-buffered in LDS (counted vmcnt, R12 skeleton).
// ---------------------------------------------------------------------------
__global__ __launch_bounds__(256, 4) void stats_kernel(
    const __bf16* __restrict__ Qb, const __bf16* __restrict__ Kb,
    float* __restrict__ Lpart, int qlen) {
  __shared__ __align__(16) __bf16 QT[2][4096];  // 2 x (64 q-rows x 64 d)
  const int b = blockIdx.y, kblk = blockIdx.x, qs = blockIdx.z;
  const int tid = threadIdx.x, wave = tid >> 6, lane = tid & 63;
  const int l32 = lane & 31, hi = lane >> 5;

  const int kbase = kblk * 128 + wave * 32;  // wave owns 32 k-rows
  bf16x8 ak[4];  // A-frag: row k = l32, d-slice w*16 + hi*8
#pragma unroll
  for (int w = 0; w < 4; ++w)
    ak[w] = *(const bf16x8*)(Kb + ((size_t)b * S_LEN + kbase + l32) * D_DIM +
                             w * 16 + hi * 8);

  const int srow = tid >> 3, t8 = tid & 7;
  const int rr0 = srow, rr1 = 32 + srow;
  const int j0 = iswz(t8, rr0), j1 = iswz(t8, rr1);

  float sacc[16];
#pragma unroll
  for (int r = 0; r < 16; ++r) sacc[r] = 0.f;
  const __bf16* Qbase = Qb + (size_t)b * S_LEN * D_DIM;
  const int qbeg = qs * qlen, qend = qbeg + qlen;

  // prologue: stage Q(0) into buf 0 (swizzled source)
  GLOAD16(Qbase + (size_t)(qbeg + rr0) * D_DIM + 8 * j0, (char*)QT[0] + tid * 16);
  GLOAD16(Qbase + (size_t)(qbeg + rr1) * D_DIM + 8 * j1,
          (char*)QT[0] + 4096 + (size_t)tid * 16);

  int cur = 0;
  for (int q0 = qbeg; q0 < qend; q0 += 64, cur ^= 1) {
    const bool nxt = (q0 + 64 < qend);
    if (nxt) {
      GLOAD16(Qbase + (size_t)(q0 + 64 + rr0) * D_DIM + 8 * j0,
              (char*)QT[cur ^ 1] + tid * 16);
      GLOAD16(Qbase + (size_t)(q0 + 64 + rr1) * D_DIM + 8 * j1,
              (char*)QT[cur ^ 1] + 4096 + (size_t)tid * 16);
      WAIT_VM(2);
    } else {
      WAIT_VM(0);
    }
    BAR();
    const char* qt = (const char*)QT[cur];
#pragma unroll
    for (int st = 0; st < 2; ++st) {  // two 32-q subtiles
      const int row = st * 32 + l32;  // B-frag: col q = l32 -> read Q row
      f32x16 t = {};
#pragma unroll
      for (int w = 0; w < 4; ++w) {
        bf16x8 bq =
            *(const bf16x8*)(qt + row * 128 + swz(2 * w + hi, row) * 16);
        t = __builtin_amdgcn_mfma_f32_32x32x16_bf16(ak[w], bq, t, 0, 0, 0);
      }
#pragma unroll
      for (int r = 0; r < 16; ++r)
        sacc[r] += __builtin_amdgcn_exp2f(t[r] * C_EXP);
    }
    BAR();
  }
  // reduce over q (lane bits 0..4), write L partials
#pragma unroll
  for (int r = 0; r < 16; ++r) {
    float v = sacc[r];
    v += __shfl_xor(v, 1);
    v += __shfl_xor(v, 2);
    v += __shfl_xor(v, 4);
    v += __shfl_xor(v, 8);
    v += __shfl_xor(v, 16);
    if (l32 == 0)
      Lpart[(size_t)qs * NB * S_LEN + (size_t)b * S_LEN + kbase + (r & 3) +
            8 * (r >> 2) + 4 * hi] = v;
  }
}

// ---------------------------------------------------------------------------
// Kernel C: Vt[b][d][k] = bf16(V[b][k][d] / L[b][k]),  L = sum of 4 partials
// ---------------------------------------------------------------------------
__global__ __launch_bounds__(256) void scalev_kernel(
    const float* __restrict__ V, const float* __restrict__ Lpart,
    __bf16* __restrict__ Vt) {
  const int b = blockIdx.y;
  const int k = blockIdx.x * 256 + threadIdx.x;
  const size_t NS = (size_t)NB * S_LEN;
  const size_t idx = (size_t)b * S_LEN + k;
  const float L =
      Lpart[idx] + Lpart[NS + idx] + Lpart[2 * NS + idx] + Lpart[3 * NS + idx];
  const float inv = 1.0f / L;
  const float* vrow = V + ((size_t)b * S_LEN + k) * D_DIM;
  __bf16* vt = Vt + (size_t)b * D_DIM * S_LEN + k;
#pragma unroll
  for (int d = 0; d < D_DIM; ++d)
    vt[(size_t)d * S_LEN] = (__bf16)(vrow[d] * inv);
}

// ---------------------------------------------------------------------------
// Kernel D: partial Out = exp(Q·K^T/8) @ Vt over a k-range (split-k).
// Swapped QK^T (32x32): mfma(K, Q) -> lane holds P[q=lane&31][k' in regs].
// P -> PV A-fragments fully in-register: cvt_pk pairs + 2x permlane32_swap
// per 16-k window (lanes l, l+32 share q, hold complementary k-halves).
// No P LDS round-trip. R12 interleaved K/V pipeline retained.
// ---------------------------------------------------------------------------
__global__ __launch_bounds__(256, 4) void attn_out_kernel(
    const __bf16* __restrict__ Qb, const __bf16* __restrict__ Kb,
    const __bf16* __restrict__ Vt, float* __restrict__ Op, int klen) {
  __shared__ __align__(16) __bf16 KT[4096];  // 64 k-rows x 64 d, swizzled
  __shared__ __align__(16) __bf16 VT[4096];  // 64 d-rows x 64 k, swizzled
  const int b = blockIdx.y, qblk = blockIdx.x, ks = blockIdx.z;
  const int tid = threadIdx.x, wave = tid >> 6, lane = tid & 63;
  const int l32 = lane & 31, hi = lane >> 5;
  const int qbase = qblk * 128 + wave * 32;  // wave owns 32 q-rows

  bf16x8 aq[4];  // QK^T B-frag: col q = l32, d-slice w*16 + hi*8
#pragma unroll
  for (int w = 0; w < 4; ++w)
    aq[w] = *(const bf16x8*)(Qb + ((size_t)b * S_LEN + qbase + l32) * D_DIM +
                             w * 16 + hi * 8);

  f32x16 acc[2] = {};  // Out: D[row=q', col=d] per 32-d tile
  const int srow = tid >> 3, t8 = tid & 7;
  const int rr0 = srow, rr1 = 32 + srow;
  const int j0 = iswz(t8, rr0), j1 = iswz(t8, rr1);
  const __bf16* Kbase = Kb + (size_t)b * S_LEN * D_DIM;
  const __bf16* Vbase = Vt + (size_t)b * D_DIM * S_LEN;
  const int kbeg = ks * klen, kend = kbeg + klen;

  // prologue: issue K(0) then V(0)  (4 DMAs outstanding)
  GLOAD16(Kbase + (size_t)(kbeg + rr0) * D_DIM + 8 * j0, (char*)KT + tid * 16);
  GLOAD16(Kbase + (size_t)(kbeg + rr1) * D_DIM + 8 * j1,
          (char*)KT + 4096 + (size_t)tid * 16);
  GLOAD16(Vbase + (size_t)rr0 * S_LEN + kbeg + 8 * j0, (char*)VT + tid * 16);
  GLOAD16(Vbase + (size_t)rr1 * S_LEN + kbeg + 8 * j1,
          (char*)VT + 4096 + (size_t)tid * 16);

  for (int k0 = kbeg; k0 < kend; k0 += 64) {
    const bool nxt = (k0 + 64 < kend);
    WAIT_VM(2);  // K(t) landed (oldest 2); V(t) may still fly
    BAR();
    bf16x8 paf[4];  // PV A-frags, one per 16-k window of this 64-k tile
#pragma unroll
    for (int st = 0; st < 2; ++st) {  // two 32-k subtiles
      const int row = st * 32 + l32;  // A-frag: row k = l32 -> read K row
      f32x16 t = {};
#pragma unroll
      for (int w = 0; w < 4; ++w) {
        bf16x8 ka =
            *(const bf16x8*)((const char*)KT + row * 128 +
                             swz(2 * w + hi, row) * 16);
        t = __builtin_amdgcn_mfma_f32_32x32x16_bf16(ka, aq[w], t, 0, 0, 0);
      }
      // t[r] = S^T[k'=(r&3)+8(r>>2)+4hi (local), q=l32]
      float p[16];
#pragma unroll
      for (int r = 0; r < 16; ++r)
        p[r] = __builtin_amdgcn_exp2f(t[r] * C_EXP);
      // pack k-consecutive pairs: c[2s+t2] = {k=8s+4hi+2t2, +1} of block s
      unsigned c[8];
#pragma unroll
      for (int s = 0; s < 4; ++s) {
        c[2 * s] = cvt_pk_bf16(p[4 * s], p[4 * s + 1]);
        c[2 * s + 1] = cvt_pk_bf16(p[4 * s + 2], p[4 * s + 3]);
      }
      // window wp covers k-blocks {2wp, 2wp+1}; lane needs full block 2wp+hi:
      // (w0,w2) = swap(c[4wp], c[4wp+2]); (w1,w3) = swap(c[4wp+1], c[4wp+3])
#pragma unroll
      for (int wp = 0; wp < 2; ++wp) {
        unsigned a0 = c[4 * wp], b0 = c[4 * wp + 2];
        PLSWAP(a0, b0);
        unsigned a1 = c[4 * wp + 1], b1 = c[4 * wp + 3];
        PLSWAP(a1, b1);
        u32x4 f = {a0, a1, b0, b1};
        paf[2 * st + wp] = __builtin_bit_cast(bf16x8, f);
      }
    }
    BAR();  // all waves done reading KT
    if (nxt) {  // K(t+1) DMA flies during PV(t)
      GLOAD16(Kbase + (size_t)(k0 + 64 + rr0) * D_DIM + 8 * j0,
              (char*)KT + tid * 16);
      GLOAD16(Kbase + (size_t)(k0 + 64 + rr1) * D_DIM + 8 * j1,
              (char*)KT + 4096 + (size_t)tid * 16);
      WAIT_VM(2);  // V(t) ready; K(t+1) in flight
    } else {
      WAIT_VM(0);
    }
    BAR();
    // PV: D[row=q', col=d] += P(A) x V'(B); B-frag: col d = l32 (+32dt),
    // k-slice win*16 + hi*8 -> read VT row d, logical slot 2win+hi
#pragma unroll
    for (int dt = 0; dt < 2; ++dt) {
      const int row = dt * 32 + l32;
#pragma unroll
      for (int win = 0; win < 4; ++win) {
        bf16x8 bv =
            *(const bf16x8*)((const char*)VT + row * 128 +
                             swz(2 * win + hi, row) * 16);
        acc[dt] =
            __builtin_amdgcn_mfma_f32_32x32x16_bf16(paf[win], bv, acc[dt], 0, 0, 0);
      }
    }
    BAR();  // all waves done reading VT
    if (nxt) {  // V(t+1) DMA flies during S(t+1)
      GLOAD16(Vbase + (size_t)rr0 * S_LEN + (k0 + 64) + 8 * j0,
              (char*)VT + tid * 16);
      GLOAD16(Vbase + (size_t)rr1 * S_LEN + (k0 + 64) + 8 * j1,
              (char*)VT + 4096 + (size_t)tid * 16);
    }
  }
  // epilogue: acc[dt][r] = Out[q = qbase+(r&3)+8(r>>2)+4hi][d = dt*32+l32]
  float* ob = Op + ((size_t)ks * NB + b) * (size_t)(S_LEN * D_DIM);
#pragma unroll
  for (int dt = 0; dt < 2; ++dt)
#pragma unroll
    for (int r = 0; r < 16; ++r)
      ob[(size_t)(qbase + (r & 3) + 8 * (r >> 2) + 4 * hi) * D_DIM + dt * 32 +
         l32] = acc[dt][r];
}

// ---------------------------------------------------------------------------
// Kernel E: reduce split-k partials (float4 vectorized, 1 elem/thread)
// ---------------------------------------------------------------------------
__global__ __launch_bounds__(256) void reduce_kernel(
    const float* __restrict__ Op, float* __restrict__ out, int np) {
  const int i = blockIdx.x * 256 + threadIdx.x;
  const int slab = NB * S_LEN * D_DIM / 4;  // float4 per slab
  const float4* p = (const float4*)Op;
  float4 s = p[i];
  for (int j = 1; j < np; ++j) {
    float4 t = p[i + (size_t)j * slab];
    s.x += t.x; s.y += t.y; s.z += t.z; s.w += t.w;
  }
  ((float4*)out)[i] = s;
}

// ---------------------------------------------------------------------------
extern "C" void kernel_launch(void* const* d_in, const int* in_sizes, int n_in,
                              void* d_out, int out_size, void* d_ws,
                              size_t ws_size, hipStream_t stream) {
  const float* q = (const float*)d_in[0];
  const float* k = (const float*)d_in[1];
  const float* v = (const float*)d_in[2];
  float* out = (float*)d_out;

  char* ws = (char*)d_ws;
  const size_t nelem = (size_t)NB * S_LEN * D_DIM;  // 2,097,152
  __bf16* Qb = (__bf16*)ws;                          // 4 MB @ 0
  __bf16* Kb = (__bf16*)(ws + nelem * 2);            // 4 MB @ 4M
  __bf16* Vt = (__bf16*)(ws + nelem * 4);            // 4 MB @ 8M
  float* Lp = (float*)(ws + nelem * 6);              // 512 KB @ 12M
  float* Op = (float*)(ws + (13u << 20));            // up to 32 MB @ 13M

  // split-k factor limited by workspace for fp32 partials
  int ksplit = 1;
  if (ws_size >= (13u << 20) + 4 * nelem * 4) ksplit = 4;
  else if (ws_size >= (13u << 20) + 2 * nelem * 4) ksplit = 2;

  convert_bf16_kernel<<<1024, 256, 0, stream>>>(q, k, Qb, Kb);
  stats_kernel<<<dim3(16, 16, 4), 256, 0, stream>>>(Qb, Kb, Lp, S_LEN / 4);
  scalev_kernel<<<dim3(8, 16), 256, 0, stream>>>(v, Lp, Vt);
  float* attn_dst = (ksplit == 1) ? out : Op;
  attn_out_kernel<<<dim3(16, 16, ksplit), 256, 0, stream>>>(Qb, Kb, Vt,
                                                            attn_dst,
                                                            S_LEN / ksplit);
  if (ksplit > 1)
    reduce_kernel<<<(int)(nelem / 4 / 256), 256, 0, stream>>>(Op, out, ksplit);
}